// Round 11
// baseline (109.819 us; speedup 1.0000x reference)
//
#include <hip/hip_runtime.h>

typedef unsigned short u16;
typedef unsigned int u32;
typedef float f32x4 __attribute__((ext_vector_type(4)));
typedef short bf16x8 __attribute__((ext_vector_type(8)));

#define AS1 __attribute__((address_space(1)))
#define AS3 __attribute__((address_space(3)))

__device__ __forceinline__ void g2l16(const void* g, void* l) {
  __builtin_amdgcn_global_load_lds((const AS1 void*)g, (AS3 void*)l, 16, 0, 0);
}

__device__ __forceinline__ u32 bfr(float f) {
  u32 u = __float_as_uint(f);
  return (u + 0x7fffu + ((u >> 16) & 1u)) >> 16;
}

#define PI_F 3.14159265358979323846f

// ---- merged converts: x -> xb (bf16), W1 -> w1t (transposed), W2 -> w2t
__global__ __launch_bounds__(256) void cvt_all(
    const float* __restrict__ x, const float* __restrict__ W1,
    const float* __restrict__ W2, u16* __restrict__ xb,
    u16* __restrict__ w1t, u16* __restrict__ w2t) {
  __shared__ u16 T[64][65];
  const int tid = threadIdx.x;
  int bid = blockIdx.x;
  if (bid < 8192) {
    long t = (long)bid * 256 + tid;
    const float4 a = ((const float4*)x)[t * 2 + 0];
    const float4 b = ((const float4*)x)[t * 2 + 1];
    uint4 o;
    o.x = bfr(a.x) | (bfr(a.y) << 16);
    o.y = bfr(a.z) | (bfr(a.w) << 16);
    o.z = bfr(b.x) | (bfr(b.y) << 16);
    o.w = bfr(b.z) | (bfr(b.w) << 16);
    ((uint4*)xb)[t] = o;
    return;
  }
  bid -= 8192;                       // 0..511
  int kt = (bid & 15) << 6;
  int nt = (bid >> 4) << 6;
  #pragma unroll
  for (int i = 0; i < 16; ++i) {
    int e = i * 256 + tid;
    int r = e >> 6, c = e & 63;
    T[r][c] = (u16)bfr(W1[(long)(kt + r) * 2048 + nt + c]);
  }
  __syncthreads();
  #pragma unroll
  for (int i = 0; i < 16; ++i) {
    int e = i * 256 + tid;
    int n = e >> 6, k = e & 63;
    w1t[(long)(nt + n) * 1024 + kt + k] = T[k][n];
  }
  if (bid < 128) {
    int idx = bid * 256 + tid;
    int k = idx >> 4, q = idx & 15;
    w2t[q * 2048 + k] = (u16)bfr(W2[idx]);
  }
}

// ==================== fused GEMM1 + E-partial, persistent 2-tile =========
// 256x256 tile, BK=64, 8 waves (2Mx4N, per-wave 128x64). Each block does
// tiles (tm,tn0) then (tm,tn0+4): same A panel (L2-warm restage), tile2.T0
// staged at tile1's t=15 and lands under epilogue1. K-loop: ONE gate
// (vmcnt(0)+barrier) per K-tile. LDS 4x32KB regions R0..R3 (A:R0/R1,
// B:R2/R3), XOR swizzle via pre-swizzled gload source. Epilogue: 2 row-
// rounds, P in R1uR3 (64KB) -> E-MFMA vs w2t; Ew [128][64] f32 half-rounds
// in R1; store Ep[tn][row][q].
__global__ __launch_bounds__(512, 2) void gemm1_fused(
    const u16* __restrict__ xb, const u16* __restrict__ w1t,
    const float* __restrict__ b1, const u16* __restrict__ w2t,
    float* __restrict__ Ep) {
  __shared__ __align__(16) char LDS[131072];
  char* const R0 = LDS;
  char* const R1 = LDS + 32768;
  char* const R2 = LDS + 65536;
  char* const R3 = LDS + 98304;

  const int bid = blockIdx.x;        // 256 blocks = 1/CU, single pass
  const int local = bid >> 3;        // 0..31 within XCD chunk
  const int tm = (bid & 7) * 8 + (local >> 2);   // 0..63
  const int tn0 = local & 3;                     // 0..3 (pair: tn0, tn0+4)
  const int tid = threadIdx.x;
  const int lane = tid & 63;
  const int wid = tid >> 6;
  const int wm = wid >> 2;           // 0..1
  const int wn = wid & 3;            // 0..3
  const int l15 = lane & 15;
  const int cg = lane >> 4;          // 0..3
  const int key = (l15 & 7) << 4;
  const int cb0 = (cg * 16) ^ key;
  const int cb1 = (64 + cg * 16) ^ key;

  const u16* Ag = xb + (long)tm * 256 * 1024;
  const u16* Bg1 = w1t + (long)tn0 * 256 * 1024;
  const u16* Bg2 = w1t + (long)(tn0 + 4) * 256 * 1024;

  bf16x8 a[4][2], b[4][2];
  f32x4 acc[8][4];
  f32x4 acc2[8];

// stage full tile t (256 rows x 64 k, 32 KB): linear LDS dest,
// inverse-swizzled global source. 512 thr x 4 x 16B.
#define STG(gm, sl, t) do {                                                  \
    _Pragma("unroll")                                                        \
    for (int i = 0; i < 4; ++i) {                                            \
      int off = i * 8192 + tid * 16;                                         \
      int row = off >> 7;                                                    \
      int cb = (off & 127) ^ ((row & 7) << 4);                               \
      g2l16((const char*)(gm) + (long)row * 2048 + (t) * 128 + cb,           \
            (sl) + off);                                                     \
    } } while (0)

#define RDA(sl, mh) do {                                                     \
    _Pragma("unroll")                                                        \
    for (int m = 0; m < 4; ++m) {                                            \
      int ro = (wm * 128 + (mh) * 64 + m * 16 + l15) * 128;                  \
      a[m][0] = *(const bf16x8*)((sl) + ro + cb0);                           \
      a[m][1] = *(const bf16x8*)((sl) + ro + cb1);                           \
    } } while (0)

#define RDB(sl) do {                                                         \
    _Pragma("unroll")                                                        \
    for (int n = 0; n < 4; ++n) {                                            \
      int ro = (wn * 64 + n * 16 + l15) * 128;                               \
      b[n][0] = *(const bf16x8*)((sl) + ro + cb0);                           \
      b[n][1] = *(const bf16x8*)((sl) + ro + cb1);                           \
    } } while (0)

#define MMh(mh) do {                                                         \
    __builtin_amdgcn_s_setprio(1);                                           \
    _Pragma("unroll")                                                        \
    for (int m = 0; m < 4; ++m)                                              \
      _Pragma("unroll")                                                      \
      for (int n = 0; n < 4; ++n) {                                          \
        acc[(mh)*4+m][n] = __builtin_amdgcn_mfma_f32_16x16x32_bf16(          \
            a[m][0], b[n][0], acc[(mh)*4+m][n], 0, 0, 0);                    \
        acc[(mh)*4+m][n] = __builtin_amdgcn_mfma_f32_16x16x32_bf16(          \
            a[m][1], b[n][1], acc[(mh)*4+m][n], 0, 0, 0);                    \
      }                                                                      \
    __builtin_amdgcn_s_setprio(0);                                           \
  } while (0)

#define BAR __builtin_amdgcn_s_barrier()

// K-loop: 1 gate/K-tile. Iter t stages t+1 (t=1..14); t=15 runs LAST_STG.
#define KLOOP(BgX, LAST_STG) do {                                            \
    _Pragma("unroll 1")                                                      \
    for (int t = 0; t < 16; ++t) {                                           \
      char* cA = (t & 1) ? R1 : R0;                                          \
      char* cB = (t & 1) ? R3 : R2;                                          \
      char* nA = (t & 1) ? R0 : R1;                                          \
      char* nB = (t & 1) ? R2 : R3;                                          \
      if (t >= 1 && t < 15) { STG(Ag, nA, t + 1); STG(BgX, nB, t + 1); }     \
      if (t == 15) { LAST_STG; }                                             \
      RDB(cB);                                                               \
      RDA(cA, 0); MMh(0);                                                    \
      RDA(cA, 1); MMh(1);                                                    \
      if (t < 15) asm volatile("s_waitcnt vmcnt(0)" ::: "memory");           \
      BAR;                                                                   \
    } } while (0)

// Epilogue for one tile with column-panel tn. P in R1uR3 (per-wave 8KB,
// 64 rows x 64 cols, 2 rounds); Ew [128][64] f32 half-rounds in R1.
#define EPILOGUE(tn) do {                                                    \
    char* Pw = (wid < 4) ? (R1 + wid * 8192) : (R3 + (wid - 4) * 8192);      \
    float bias[4];                                                           \
    _Pragma("unroll")                                                        \
    for (int n = 0; n < 4; ++n)                                              \
      bias[n] = b1[(tn) * 256 + wn * 64 + n * 16 + l15];                     \
    const u16* w2p = w2t + l15 * 2048 + (tn) * 256 + wn * 64;                \
    bf16x8 bw0 = *(const bf16x8*)(w2p + cg * 8);                             \
    bf16x8 bw1 = *(const bf16x8*)(w2p + 32 + cg * 8);                        \
    _Pragma("unroll")                                                        \
    for (int r = 0; r < 2; ++r) {                                            \
      _Pragma("unroll")                                                      \
      for (int n = 0; n < 4; ++n)                                            \
        _Pragma("unroll")                                                    \
        for (int m4 = 0; m4 < 4; ++m4)                                       \
          _Pragma("unroll")                                                  \
          for (int jj = 0; jj < 4; ++jj) {                                   \
            int row = m4 * 16 + cg * 4 + jj;                                 \
            float v = acc[r * 4 + m4][n][jj] + bias[n];                      \
            v = v > 0.f ? v : 0.f;                                           \
            int cbyte = ((n * 16 + l15) * 2) ^ ((row & 7) << 4);             \
            *(u16*)(Pw + row * 128 + cbyte) = (u16)bfr(v);                   \
          }                                                                  \
      _Pragma("unroll")                                                      \
      for (int m4 = 0; m4 < 4; ++m4) {                                       \
        bf16x8 a0 = *(const bf16x8*)(Pw + (m4 * 16 + l15) * 128 +            \
                                     ((cg * 16) ^ key));                     \
        bf16x8 a1 = *(const bf16x8*)(Pw + (m4 * 16 + l15) * 128 +            \
                                     ((64 + cg * 16) ^ key));                \
        f32x4 z = {0.f, 0.f, 0.f, 0.f};                                      \
        z = __builtin_amdgcn_mfma_f32_16x16x32_bf16(a0, bw0, z, 0, 0, 0);    \
        z = __builtin_amdgcn_mfma_f32_16x16x32_bf16(a1, bw1, z, 0, 0, 0);    \
        acc2[r * 4 + m4] = z;                                                \
      }                                                                      \
    }                                                                        \
    __syncthreads();                                                         \
    float* Ew = (float*)R1;                                                  \
    _Pragma("unroll")                                                        \
    for (int wmh = 0; wmh < 2; ++wmh) {                                      \
      if (wm == wmh) {                                                       \
        _Pragma("unroll")                                                    \
        for (int mf = 0; mf < 8; ++mf)                                       \
          _Pragma("unroll")                                                  \
          for (int rg = 0; rg < 4; ++rg)                                     \
            Ew[(mf * 16 + cg * 4 + rg) * 64 + l15 * 4 + wn] = acc2[mf][rg];  \
      }                                                                      \
      __syncthreads();                                                       \
      _Pragma("unroll")                                                      \
      for (int c = tid; c < 2048; c += 512) {                                \
        int row = c >> 4, q = c & 15;                                        \
        const float* e4 = &Ew[row * 64 + q * 4];                             \
        float s = e4[0] + e4[1] + e4[2] + e4[3];                             \
        Ep[(long)(tn) * (16384 * 16) +                                       \
           (long)(tm * 256 + wmh * 128 + row) * 16 + q] = s;                 \
      }                                                                      \
      __syncthreads();                                                       \
    } } while (0)

  // ---------------- tile 1: (tm, tn0) ----------------
  #pragma unroll
  for (int m = 0; m < 8; ++m)
    #pragma unroll
    for (int n = 0; n < 4; ++n) acc[m][n] = (f32x4){0.f, 0.f, 0.f, 0.f};

  STG(Ag, R0, 0); STG(Bg1, R2, 0);    // T0
  STG(Ag, R1, 1); STG(Bg1, R3, 1);    // T1
  asm volatile("s_waitcnt vmcnt(8)" ::: "memory");   // T0 landed
  BAR;
  KLOOP(Bg1, { STG(Ag, nA, 0); STG(Bg2, nB, 0); });  // t=15 preloads tile2.T0
  EPILOGUE(tn0);

  // ---------------- tile 2: (tm, tn0+4) --------------
  #pragma unroll
  for (int m = 0; m < 8; ++m)
    #pragma unroll
    for (int n = 0; n < 4; ++n) acc[m][n] = (f32x4){0.f, 0.f, 0.f, 0.f};

  STG(Ag, R1, 1); STG(Bg2, R3, 1);    // T1 (T0 already resident in R0/R2)
  asm volatile("s_waitcnt vmcnt(8)" ::: "memory");   // everything except T1
  BAR;
  KLOOP(Bg2, {});
  EPILOGUE(tn0 + 4);

#undef STG
#undef RDA
#undef RDB
#undef MMh
#undef BAR
#undef KLOOP
#undef EPILOGUE
}

// ---------------- final: sum Ep, +b2, tanh, sin, VQC, sigmoid -------------
__global__ __launch_bounds__(256) void vqc_final(
    const float* __restrict__ Ep, const float* __restrict__ b2,
    const float* __restrict__ vqc, const float* __restrict__ Wd,
    const float* __restrict__ bd, float* __restrict__ out) {
  const int tid = threadIdx.x;
  const int lane = tid & 63;
  const int wave = tid >> 6;
  const int q = lane & 15;
  const int g = lane >> 4;
  const int row = blockIdx.x * 16 + wave * 4 + g;

  float e = 0.f;
  #pragma unroll
  for (int p = 0; p < 8; ++p)
    e += Ep[(long)p * (16384 * 16) + (long)row * 16 + q];

  float ct[6], sp[6];
  #pragma unroll
  for (int L = 0; L < 6; ++L) {
    float th = vqc[(L * 16 + q) * 2 + 0];
    float ph = vqc[(L * 16 + q) * 2 + 1];
    ct[L] = __cosf(th);
    sp[L] = __sinf(th) * __cosf(ph);
  }
  float s = __sinf(tanhf(e + b2[q]) * PI_F);
  #pragma unroll
  for (int L = 0; L < 6; ++L) {
    s = ct[L] * s + sp[L];
    if (L < 5) {
      float ps = __shfl_xor(s, 1, 64);
      s = (q & 1) ? (0.1f * ps + 0.9f * s) : s;
    }
  }
  float p = s * Wd[q];
  p += __shfl_xor(p, 1, 64);
  p += __shfl_xor(p, 2, 64);
  p += __shfl_xor(p, 4, 64);
  p += __shfl_xor(p, 8, 64);
  if (q == 0) out[row] = 1.f / (1.f + __expf(-(p + bd[0])));
}

// ---------------- fp32 fallback (ws too small): slow but correct ---------
__global__ __launch_bounds__(256) void fallback(
    const float* __restrict__ x, const float* __restrict__ W1,
    const float* __restrict__ b1, const float* __restrict__ W2,
    const float* __restrict__ b2, const float* __restrict__ vqc,
    const float* __restrict__ Wd, const float* __restrict__ bd,
    float* __restrict__ out) {
  __shared__ float xs[4][1024];
  __shared__ float E[4][16];
  const int bid = blockIdx.x;
  const int tid = threadIdx.x;
  const int r0 = bid * 4;
  for (int i = tid; i < 4 * 1024; i += 256)
    xs[i >> 10][i & 1023] = x[(long)(r0 + (i >> 10)) * 1024 + (i & 1023)];
  if (tid < 64) ((float*)E)[tid] = 0.f;
  __syncthreads();
  float pE[4][16];
  #pragma unroll
  for (int r = 0; r < 4; ++r)
    #pragma unroll
    for (int qq = 0; qq < 16; ++qq) pE[r][qq] = 0.f;
  for (int jj = 0; jj < 8; ++jj) {
    int j = jj * 256 + tid;
    float h0 = 0, h1 = 0, h2 = 0, h3 = 0;
    for (int k = 0; k < 1024; ++k) {
      float w = W1[(long)k * 2048 + j];
      h0 += xs[0][k] * w; h1 += xs[1][k] * w; h2 += xs[2][k] * w; h3 += xs[3][k] * w;
    }
    float hh[4] = {h0, h1, h2, h3};
    #pragma unroll
    for (int r = 0; r < 4; ++r) {
      float hr = hh[r] + b1[j];
      hr = hr > 0.f ? hr : 0.f;
      #pragma unroll
      for (int qq = 0; qq < 16; ++qq) pE[r][qq] += hr * W2[j * 16 + qq];
    }
  }
  #pragma unroll
  for (int r = 0; r < 4; ++r)
    #pragma unroll
    for (int qq = 0; qq < 16; ++qq) atomicAdd(&E[r][qq], pE[r][qq]);
  __syncthreads();
  if (tid < 4) {
    int r = tid;
    float s[16];
    #pragma unroll
    for (int qq = 0; qq < 16; ++qq)
      s[qq] = __sinf(tanhf(E[r][qq] + b2[qq]) * PI_F);
    #pragma unroll
    for (int L = 0; L < 6; ++L) {
      #pragma unroll
      for (int qq = 0; qq < 16; ++qq)
        s[qq] = __cosf(vqc[(L * 16 + qq) * 2]) * s[qq] +
                __sinf(vqc[(L * 16 + qq) * 2]) * __cosf(vqc[(L * 16 + qq) * 2 + 1]);
      if (L < 5)
        #pragma unroll
        for (int qq = 1; qq < 16; qq += 2) s[qq] = 0.1f * s[qq - 1] + 0.9f * s[qq];
    }
    float z = bd[0];
    #pragma unroll
    for (int qq = 0; qq < 16; ++qq) z += s[qq] * Wd[qq];
    out[r0 + r] = 1.f / (1.f + __expf(-z));
  }
}

extern "C" void kernel_launch(void* const* d_in, const int* in_sizes, int n_in,
                              void* d_out, int out_size, void* d_ws, size_t ws_size,
                              hipStream_t stream) {
  const float* x   = (const float*)d_in[0];
  const float* W1  = (const float*)d_in[1];
  const float* b1  = (const float*)d_in[2];
  const float* W2  = (const float*)d_in[3];
  const float* b2  = (const float*)d_in[4];
  const float* vqc = (const float*)d_in[5];
  const float* Wd  = (const float*)d_in[6];
  const float* bd  = (const float*)d_in[7];
  float* out = (float*)d_out;

  const size_t OFF_XB  = 0;                         // 33554432
  const size_t OFF_W1T = 33554432;                  // +4194304
  const size_t OFF_W2T = 37748736;                  // +65536
  const size_t OFF_EP  = 37814272;                  // +8388608
  const size_t NEED    = 46202880;

  if (ws_size < NEED) {
    fallback<<<4096, 256, 0, stream>>>(x, W1, b1, W2, b2, vqc, Wd, bd, out);
    return;
  }
  u16*   xb  = (u16*)((char*)d_ws + OFF_XB);
  u16*   w1t = (u16*)((char*)d_ws + OFF_W1T);
  u16*   w2t = (u16*)((char*)d_ws + OFF_W2T);
  float* Ep  = (float*)((char*)d_ws + OFF_EP);

  cvt_all<<<8704, 256, 0, stream>>>(x, W1, W2, xb, w1t, w2t);
  gemm1_fused<<<256, 512, 0, stream>>>(xb, w1t, b1, w2t, Ep);
  vqc_final<<<1024, 256, 0, stream>>>(Ep, b2, vqc, Wd, bd, out);
}

// Round 12
// 95.319 us; speedup vs baseline: 1.1521x; 1.1521x over previous
//
#include <hip/hip_runtime.h>

typedef unsigned short u16;
typedef unsigned int u32;
typedef float f32x4 __attribute__((ext_vector_type(4)));
typedef float f32x16 __attribute__((ext_vector_type(16)));
typedef short bf16x8 __attribute__((ext_vector_type(8)));

#define AS1 __attribute__((address_space(1)))
#define AS3 __attribute__((address_space(3)))

__device__ __forceinline__ void g2l16(const void* g, void* l) {
  __builtin_amdgcn_global_load_lds((const AS1 void*)g, (AS3 void*)l, 16, 0, 0);
}

__device__ __forceinline__ u32 bfr(float f) {
  u32 u = __float_as_uint(f);
  return (u + 0x7fffu + ((u >> 16) & 1u)) >> 16;
}

#define PI_F 3.14159265358979323846f

// ---- merged converts: x -> xb (bf16), W1 -> w1t (transposed), W2 -> w2t
__global__ __launch_bounds__(256) void cvt_all(
    const float* __restrict__ x, const float* __restrict__ W1,
    const float* __restrict__ W2, u16* __restrict__ xb,
    u16* __restrict__ w1t, u16* __restrict__ w2t) {
  __shared__ u16 T[64][65];
  const int tid = threadIdx.x;
  int bid = blockIdx.x;
  if (bid < 8192) {
    long t = (long)bid * 256 + tid;
    const float4 a = ((const float4*)x)[t * 2 + 0];
    const float4 b = ((const float4*)x)[t * 2 + 1];
    uint4 o;
    o.x = bfr(a.x) | (bfr(a.y) << 16);
    o.y = bfr(a.z) | (bfr(a.w) << 16);
    o.z = bfr(b.x) | (bfr(b.y) << 16);
    o.w = bfr(b.z) | (bfr(b.w) << 16);
    ((uint4*)xb)[t] = o;
    return;
  }
  bid -= 8192;                       // 0..511
  int kt = (bid & 15) << 6;
  int nt = (bid >> 4) << 6;
  #pragma unroll
  for (int i = 0; i < 16; ++i) {
    int e = i * 256 + tid;
    int r = e >> 6, c = e & 63;
    T[r][c] = (u16)bfr(W1[(long)(kt + r) * 2048 + nt + c]);
  }
  __syncthreads();
  #pragma unroll
  for (int i = 0; i < 16; ++i) {
    int e = i * 256 + tid;
    int n = e >> 6, k = e & 63;
    w1t[(long)(nt + n) * 1024 + kt + k] = T[k][n];
  }
  if (bid < 128) {
    int idx = bid * 256 + tid;
    int k = idx >> 4, q = idx & 15;
    w2t[q * 2048 + k] = (u16)bfr(W2[idx]);
  }
}

// ==================== fused GEMM1 + E-partial =============================
// r5 schedule (best measured) + 32x32x16 MFMA (2495 vs 2176 TF ubench:
// ~18% less MFMA-pipe time, identical LDS traffic & registers).
// 256x256 tile, BK=64, 8 waves (2Mx4N, per-wave 128x64, acc = 4x2 f32x16).
// 4 phases / 2 K-tiles, no mid-phase barrier, GATE(8) counted-vmcnt.
// Epilogue: P=relu(acc+b1)->bf16 in LDS (32x32 C-layout aware store),
// E-MFMA (16x16x32) vs w2t, wn-reduce, store Ep[tn][row][q] f32.
__global__ __launch_bounds__(512, 2) void gemm1_fused(
    const u16* __restrict__ xb, const u16* __restrict__ w1t,
    const float* __restrict__ b1, const u16* __restrict__ w2t,
    float* __restrict__ Ep) {
  __shared__ __align__(16) char LDS[131072];
  char* const lA0 = LDS;            // slot0 A: 2 halves x 16 KB
  char* const lA1 = LDS + 32768;    // slot1 A
  char* const lB0 = LDS + 65536;    // slot0 B
  char* const lB1 = LDS + 98304;    // slot1 B

  const int bswz = (blockIdx.x & 7) * 64 + (blockIdx.x >> 3);
  const int tm = bswz >> 3;          // 0..63
  const int tn = bswz & 7;           // 0..7
  const int tid = threadIdx.x;
  const int lane = tid & 63;
  const int wid = tid >> 6;
  const int wm = wid >> 2;           // 0..1
  const int wn = wid & 3;            // 0..3
  const int l15 = lane & 15;
  const int cg = lane >> 4;          // 0..3 (16x16 epilogue path)
  const int l31 = lane & 31;
  const int hi = lane >> 5;          // 0..1 (32x32 path)
  const int key = (l15 & 7) << 4;    // epilogue read swizzle
  const int key32 = (l31 & 7) << 4;  // main-loop read swizzle

  const u16* Ag = xb + (long)tm * 256 * 1024;
  const u16* Bg = w1t + (long)tn * 256 * 1024;

  bf16x8 a[2][4];        // current mh: 2 mf x 4 ks
  bf16x8 b[2][4];        // 2 nh x 4 ks
  f32x16 acc[4][2] = {}; // [mh*2+mf][nh]

// stage one read-half of A tile t (128 rows: bit6==h splice), linear LDS
// dest, inverse-swizzled global source (involution of read-side XOR)
#define STGA(sl, t, h) do {                                                  \
    _Pragma("unroll")                                                        \
    for (int rr = 0; rr < 2; ++rr) {                                         \
      int off = rr * 8192 + tid * 16;                                        \
      int rh = off >> 7;                                                     \
      int r = ((rh >> 6) << 7) + (h) * 64 + (rh & 63);                       \
      int cb = (off & 127) ^ ((r & 7) << 4);                                 \
      g2l16((const char*)Ag + (long)r * 2048 + (t) * 128 + cb,               \
            (sl) + (h) * 16384 + off);                                       \
    } } while (0)

// stage one read-half of B tile t (128 rows: bit5==h splice)
#define STGB(sl, t, h) do {                                                  \
    _Pragma("unroll")                                                        \
    for (int rr = 0; rr < 2; ++rr) {                                         \
      int off = rr * 8192 + tid * 16;                                        \
      int rh = off >> 7;                                                     \
      int r = ((rh >> 5) << 6) + (h) * 32 + (rh & 31);                       \
      int cb = (off & 127) ^ ((r & 7) << 4);                                 \
      g2l16((const char*)Bg + (long)r * 2048 + (t) * 128 + cb,               \
            (sl) + (h) * 16384 + off);                                       \
    } } while (0)

// A frags (32x32x16): row = wm*64 + mf*32 + l31 (within half mh),
// k byte = ks*32 + hi*16, swizzled
#define RDA(sl, mh) do {                                                     \
    _Pragma("unroll")                                                        \
    for (int mf = 0; mf < 2; ++mf) {                                         \
      int ro = (wm * 64 + mf * 32 + l31) * 128 + (mh) * 16384;               \
      _Pragma("unroll")                                                      \
      for (int ks = 0; ks < 4; ++ks)                                         \
        a[mf][ks] = *(const bf16x8*)((sl) + ro +                             \
                                     ((ks * 32 + hi * 16) ^ key32));         \
    } } while (0)

// B frags: within-half row = wn*32 + l31, half = nh
#define RDB(sl, nh) do {                                                     \
    int ro = (wn * 32 + l31) * 128 + (nh) * 16384;                           \
    _Pragma("unroll")                                                        \
    for (int ks = 0; ks < 4; ++ks)                                           \
      b[nh][ks] = *(const bf16x8*)((sl) + ro +                               \
                                   ((ks * 32 + hi * 16) ^ key32));           \
  } while (0)

// 16 MFMA (32x32x16): one mh half x 2 mf x 2 nh x 4 ks
#define MM2(mh) do {                                                         \
    __builtin_amdgcn_s_setprio(1);                                           \
    _Pragma("unroll")                                                        \
    for (int mf = 0; mf < 2; ++mf)                                           \
      _Pragma("unroll")                                                      \
      for (int nh = 0; nh < 2; ++nh)                                         \
        _Pragma("unroll")                                                    \
        for (int ks = 0; ks < 4; ++ks)                                       \
          acc[(mh)*2+mf][nh] = __builtin_amdgcn_mfma_f32_32x32x16_bf16(      \
              a[mf][ks], b[nh][ks], acc[(mh)*2+mf][nh], 0, 0, 0);            \
    __builtin_amdgcn_s_setprio(0);                                           \
  } while (0)

#define SB  __builtin_amdgcn_sched_barrier(0)
#define BAR __builtin_amdgcn_s_barrier()
#define GATE(n) do { SB;                                                     \
    asm volatile("s_waitcnt vmcnt(" #n ")" ::: "memory");                    \
    BAR; SB; } while (0)

  // prologue: 14 loads, FIFO-ordered 6/2/6 so steady-state vmcnt(8) holds.
  STGA(lA0, 0, 0); STGB(lB0, 0, 0); STGB(lB0, 0, 1);   // ph1(j0) reads
  STGA(lA0, 0, 1);                                     // ph2(j0) reads
  STGA(lA1, 1, 0); STGB(lB1, 1, 0); STGB(lB1, 1, 1);   // ph3(j0) reads
  GATE(8);                                             // first 6 landed

  #pragma unroll 1
  for (int j = 0; j < 8; ++j) {
    const int ta2 = 2 * j + 2, tb2 = 2 * j + 3;
    const bool pf = (j < 7);
    // ---- ph1: stage A1.h1(2j+1); read slot0 A.h0 + B(all); MM(0,*)
    STGA(lA1, 2 * j + 1, 1);
    RDA(lA0, 0); RDB(lB0, 0); RDB(lB0, 1);
    MM2(0);
    GATE(8);
    // ---- ph2: stage A0.h0 + B0(both) of ta2; read slot0 A.h1; MM(1,*)
    if (pf) { STGA(lA0, ta2, 0); STGB(lB0, ta2, 0); STGB(lB0, ta2, 1); }
    RDA(lA0, 1);
    MM2(1);
    if (pf) GATE(8); else GATE(2);
    // ---- ph3: stage A0.h1(ta2); read slot1 A.h0 + B(all); MM(0,*)
    if (pf) STGA(lA0, ta2, 1);
    RDA(lA1, 0); RDB(lB1, 0); RDB(lB1, 1);
    MM2(0);
    if (pf) GATE(8); else GATE(0);
    // ---- ph4: stage A1.h0 + B1(both) of tb2; read slot1 A.h1; MM(1,*)
    if (pf) { STGA(lA1, tb2, 0); STGB(lB1, tb2, 0); STGB(lB1, tb2, 1); }
    RDA(lA1, 1);
    MM2(1);
    if (pf) GATE(8); else GATE(0);
  }

  // ============== epilogue: E-partial = relu(acc+b1) @ W2slice ===========
  // P per-wave region (16 KB): 128 rows x 64 cols bf16, 128-B-row swizzle.
  // 32x32 C-layout: col = nh*32 + l31, row = f*32 + (reg&3)+8*(reg>>2)+4*hi
  char* Pw = LDS + wid * 16384;
  #pragma unroll
  for (int nh = 0; nh < 2; ++nh) {
    const float bias = b1[tn * 256 + wn * 64 + nh * 32 + l31];
    const int colb = (nh * 32 + l31) * 2;
    #pragma unroll
    for (int f = 0; f < 4; ++f) {
      #pragma unroll
      for (int reg = 0; reg < 16; ++reg) {
        int row = f * 32 + (reg & 3) + 8 * (reg >> 2) + 4 * hi;
        float v = acc[f][nh][reg] + bias;
        v = v > 0.f ? v : 0.f;
        *(u16*)(Pw + row * 128 + (colb ^ ((row & 7) << 4))) = (u16)bfr(v);
      }
    }
  }
  // B-frags: W2^T[q = l15][k within this wave's 64-col slice] (16x16x32)
  const u16* w2p = w2t + l15 * 2048 + tn * 256 + wn * 64;
  bf16x8 bw0 = *(const bf16x8*)(w2p + cg * 8);
  bf16x8 bw1 = *(const bf16x8*)(w2p + 32 + cg * 8);
  f32x4 acc2[8];
  #pragma unroll
  for (int mf = 0; mf < 8; ++mf) {
    bf16x8 a0 = *(const bf16x8*)(Pw + (mf * 16 + l15) * 128 + ((cg * 16) ^ key));
    bf16x8 a1 = *(const bf16x8*)(Pw + (mf * 16 + l15) * 128 + ((64 + cg * 16) ^ key));
    f32x4 z = {0.f, 0.f, 0.f, 0.f};
    z = __builtin_amdgcn_mfma_f32_16x16x32_bf16(a0, bw0, z, 0, 0, 0);
    z = __builtin_amdgcn_mfma_f32_16x16x32_bf16(a1, bw1, z, 0, 0, 0);
    acc2[mf] = z;
  }
  __syncthreads();   // all P reads done before Ew overwrites LDS
  // Ew[wm][128 rows][16 q x 4 wn (+4 pad)] f32, stride 68
  float* Ew = (float*)LDS;
  #pragma unroll
  for (int mf = 0; mf < 8; ++mf)
    #pragma unroll
    for (int rg = 0; rg < 4; ++rg)
      Ew[(wm * 128 + mf * 16 + cg * 4 + rg) * 68 + l15 * 4 + wn] = acc2[mf][rg];
  __syncthreads();
  // reduce over wn, store Ep[tn][tm*256 + wmh*128 + row][q]
  #pragma unroll
  for (int c = tid; c < 4096; c += 512) {
    int wmh = c >> 11, row = (c >> 4) & 127, q = c & 15;
    const float* e4 = &Ew[(wmh * 128 + row) * 68 + q * 4];
    float s = e4[0] + e4[1] + e4[2] + e4[3];
    Ep[(long)tn * (16384 * 16) + (long)(tm * 256 + wmh * 128 + row) * 16 + q] = s;
  }
#undef STGA
#undef STGB
#undef RDA
#undef RDB
#undef MM2
#undef SB
#undef BAR
#undef GATE
}

// ---------------- final: sum Ep, +b2, tanh, sin, VQC, sigmoid -------------
__global__ __launch_bounds__(256) void vqc_final(
    const float* __restrict__ Ep, const float* __restrict__ b2,
    const float* __restrict__ vqc, const float* __restrict__ Wd,
    const float* __restrict__ bd, float* __restrict__ out) {
  const int tid = threadIdx.x;
  const int lane = tid & 63;
  const int wave = tid >> 6;
  const int q = lane & 15;
  const int g = lane >> 4;
  const int row = blockIdx.x * 16 + wave * 4 + g;

  float e = 0.f;
  #pragma unroll
  for (int p = 0; p < 8; ++p)
    e += Ep[(long)p * (16384 * 16) + (long)row * 16 + q];

  float ct[6], sp[6];
  #pragma unroll
  for (int L = 0; L < 6; ++L) {
    float th = vqc[(L * 16 + q) * 2 + 0];
    float ph = vqc[(L * 16 + q) * 2 + 1];
    ct[L] = __cosf(th);
    sp[L] = __sinf(th) * __cosf(ph);
  }
  float s = __sinf(tanhf(e + b2[q]) * PI_F);
  #pragma unroll
  for (int L = 0; L < 6; ++L) {
    s = ct[L] * s + sp[L];
    if (L < 5) {
      float ps = __shfl_xor(s, 1, 64);
      s = (q & 1) ? (0.1f * ps + 0.9f * s) : s;
    }
  }
  float p = s * Wd[q];
  p += __shfl_xor(p, 1, 64);
  p += __shfl_xor(p, 2, 64);
  p += __shfl_xor(p, 4, 64);
  p += __shfl_xor(p, 8, 64);
  if (q == 0) out[row] = 1.f / (1.f + __expf(-(p + bd[0])));
}

// ---------------- fp32 fallback (ws too small): slow but correct ---------
__global__ __launch_bounds__(256) void fallback(
    const float* __restrict__ x, const float* __restrict__ W1,
    const float* __restrict__ b1, const float* __restrict__ W2,
    const float* __restrict__ b2, const float* __restrict__ vqc,
    const float* __restrict__ Wd, const float* __restrict__ bd,
    float* __restrict__ out) {
  __shared__ float xs[4][1024];
  __shared__ float E[4][16];
  const int bid = blockIdx.x;
  const int tid = threadIdx.x;
  const int r0 = bid * 4;
  for (int i = tid; i < 4 * 1024; i += 256)
    xs[i >> 10][i & 1023] = x[(long)(r0 + (i >> 10)) * 1024 + (i & 1023)];
  if (tid < 64) ((float*)E)[tid] = 0.f;
  __syncthreads();
  float pE[4][16];
  #pragma unroll
  for (int r = 0; r < 4; ++r)
    #pragma unroll
    for (int qq = 0; qq < 16; ++qq) pE[r][qq] = 0.f;
  for (int jj = 0; jj < 8; ++jj) {
    int j = jj * 256 + tid;
    float h0 = 0, h1 = 0, h2 = 0, h3 = 0;
    for (int k = 0; k < 1024; ++k) {
      float w = W1[(long)k * 2048 + j];
      h0 += xs[0][k] * w; h1 += xs[1][k] * w; h2 += xs[2][k] * w; h3 += xs[3][k] * w;
    }
    float hh[4] = {h0, h1, h2, h3};
    #pragma unroll
    for (int r = 0; r < 4; ++r) {
      float hr = hh[r] + b1[j];
      hr = hr > 0.f ? hr : 0.f;
      #pragma unroll
      for (int qq = 0; qq < 16; ++qq) pE[r][qq] += hr * W2[j * 16 + qq];
    }
  }
  #pragma unroll
  for (int r = 0; r < 4; ++r)
    #pragma unroll
    for (int qq = 0; qq < 16; ++qq) atomicAdd(&E[r][qq], pE[r][qq]);
  __syncthreads();
  if (tid < 4) {
    int r = tid;
    float s[16];
    #pragma unroll
    for (int qq = 0; qq < 16; ++qq)
      s[qq] = __sinf(tanhf(E[r][qq] + b2[qq]) * PI_F);
    #pragma unroll
    for (int L = 0; L < 6; ++L) {
      #pragma unroll
      for (int qq = 0; qq < 16; ++qq)
        s[qq] = __cosf(vqc[(L * 16 + qq) * 2]) * s[qq] +
                __sinf(vqc[(L * 16 + qq) * 2]) * __cosf(vqc[(L * 16 + qq) * 2 + 1]);
      if (L < 5)
        #pragma unroll
        for (int qq = 1; qq < 16; qq += 2) s[qq] = 0.1f * s[qq - 1] + 0.9f * s[qq];
    }
    float z = bd[0];
    #pragma unroll
    for (int qq = 0; qq < 16; ++qq) z += s[qq] * Wd[qq];
    out[r0 + r] = 1.f / (1.f + __expf(-z));
  }
}

extern "C" void kernel_launch(void* const* d_in, const int* in_sizes, int n_in,
                              void* d_out, int out_size, void* d_ws, size_t ws_size,
                              hipStream_t stream) {
  const float* x   = (const float*)d_in[0];
  const float* W1  = (const float*)d_in[1];
  const float* b1  = (const float*)d_in[2];
  const float* W2  = (const float*)d_in[3];
  const float* b2  = (const float*)d_in[4];
  const float* vqc = (const float*)d_in[5];
  const float* Wd  = (const float*)d_in[6];
  const float* bd  = (const float*)d_in[7];
  float* out = (float*)d_out;

  const size_t OFF_XB  = 0;                         // 33554432
  const size_t OFF_W1T = 33554432;                  // +4194304
  const size_t OFF_W2T = 37748736;                  // +65536
  const size_t OFF_EP  = 37814272;                  // +8388608
  const size_t NEED    = 46202880;

  if (ws_size < NEED) {
    fallback<<<4096, 256, 0, stream>>>(x, W1, b1, W2, b2, vqc, Wd, bd, out);
    return;
  }
  u16*   xb  = (u16*)((char*)d_ws + OFF_XB);
  u16*   w1t = (u16*)((char*)d_ws + OFF_W1T);
  u16*   w2t = (u16*)((char*)d_ws + OFF_W2T);
  float* Ep  = (float*)((char*)d_ws + OFF_EP);

  cvt_all<<<8704, 256, 0, stream>>>(x, W1, W2, xb, w1t, w2t);
  gemm1_fused<<<512, 512, 0, stream>>>(xb, w1t, b1, w2t, Ep);
  vqc_final<<<1024, 256, 0, stream>>>(Ep, b2, vqc, Wd, bd, out);
}

// Round 13
// 88.354 us; speedup vs baseline: 1.2429x; 1.0788x over previous
//
#include <hip/hip_runtime.h>

typedef unsigned short u16;
typedef unsigned int u32;
typedef float f32x4 __attribute__((ext_vector_type(4)));
typedef short bf16x8 __attribute__((ext_vector_type(8)));

#define AS1 __attribute__((address_space(1)))
#define AS3 __attribute__((address_space(3)))

__device__ __forceinline__ void g2l16(const void* g, void* l) {
  __builtin_amdgcn_global_load_lds((const AS1 void*)g, (AS3 void*)l, 16, 0, 0);
}

__device__ __forceinline__ u32 bfr(float f) {
  u32 u = __float_as_uint(f);
  return (u + 0x7fffu + ((u >> 16) & 1u)) >> 16;
}

#define PI_F 3.14159265358979323846f

// ---- merged converts: x -> xb (bf16), W1 -> w1t (transposed), W2 -> w2t
__global__ __launch_bounds__(256) void cvt_all(
    const float* __restrict__ x, const float* __restrict__ W1,
    const float* __restrict__ W2, u16* __restrict__ xb,
    u16* __restrict__ w1t, u16* __restrict__ w2t) {
  __shared__ u16 T[64][65];
  const int tid = threadIdx.x;
  int bid = blockIdx.x;
  if (bid < 8192) {
    long t = (long)bid * 256 + tid;
    const float4 a = ((const float4*)x)[t * 2 + 0];
    const float4 b = ((const float4*)x)[t * 2 + 1];
    uint4 o;
    o.x = bfr(a.x) | (bfr(a.y) << 16);
    o.y = bfr(a.z) | (bfr(a.w) << 16);
    o.z = bfr(b.x) | (bfr(b.y) << 16);
    o.w = bfr(b.z) | (bfr(b.w) << 16);
    ((uint4*)xb)[t] = o;
    return;
  }
  bid -= 8192;                       // 0..511
  int kt = (bid & 15) << 6;
  int nt = (bid >> 4) << 6;
  #pragma unroll
  for (int i = 0; i < 16; ++i) {
    int e = i * 256 + tid;
    int r = e >> 6, c = e & 63;
    T[r][c] = (u16)bfr(W1[(long)(kt + r) * 2048 + nt + c]);
  }
  __syncthreads();
  #pragma unroll
  for (int i = 0; i < 16; ++i) {
    int e = i * 256 + tid;
    int n = e >> 6, k = e & 63;
    w1t[(long)(nt + n) * 1024 + kt + k] = T[k][n];
  }
  if (bid < 128) {
    int idx = bid * 256 + tid;
    int k = idx >> 4, q = idx & 15;
    w2t[q * 2048 + k] = (u16)bfr(W2[idx]);
  }
}

// ==================== fused GEMM1 + E-partial =============================
// BEST-MEASURED structure (r5, gemm 69.4us): 256x256 tile, BK=64, 8 waves
// (2Mx4N, per-wave 128x64). 4 phases / 2 K-tiles, NO mid-phase barrier;
// one gate per phase: sched_barrier + vmcnt(8) + s_barrier + sched_barrier.
// Stage-into-freed-half schedule, 16x16x32 MFMA (bank-balanced reads).
// Epilogue: P=relu(acc+b1)->bf16 in LDS (swizzled), E-MFMA vs w2t,
// wn-reduce in LDS, store Ep[tn][row][q] f32.
__global__ __launch_bounds__(512, 2) void gemm1_fused(
    const u16* __restrict__ xb, const u16* __restrict__ w1t,
    const float* __restrict__ b1, const u16* __restrict__ w2t,
    float* __restrict__ Ep) {
  __shared__ __align__(16) char LDS[131072];
  char* const lA0 = LDS;            // slot0 A: 2 halves x 16 KB
  char* const lA1 = LDS + 32768;    // slot1 A
  char* const lB0 = LDS + 65536;    // slot0 B
  char* const lB1 = LDS + 98304;    // slot1 B

  const int bswz = (blockIdx.x & 7) * 64 + (blockIdx.x >> 3);
  const int tm = bswz >> 3;          // 0..63
  const int tn = bswz & 7;           // 0..7
  const int tid = threadIdx.x;
  const int lane = tid & 63;
  const int wid = tid >> 6;
  const int wm = wid >> 2;           // 0..1
  const int wn = wid & 3;            // 0..3
  const int l15 = lane & 15;
  const int cg = lane >> 4;          // 0..3
  const int key = (l15 & 7) << 4;    // read-side swizzle XOR (bytes)
  const int cb0 = (cg * 16) ^ key;
  const int cb1 = (64 + cg * 16) ^ key;

  const u16* Ag = xb + (long)tm * 256 * 1024;
  const u16* Bg = w1t + (long)tn * 256 * 1024;

  bf16x8 a[4][2];
  bf16x8 b[2][2][2];
  f32x4 acc[8][4] = {};

// stage one read-half of A tile t into slot base sl (linear LDS dest,
// inverse-swizzled global source). rh 0..127 -> global row bit-splice.
#define STGA(sl, t, h) do {                                                  \
    _Pragma("unroll")                                                        \
    for (int rr = 0; rr < 2; ++rr) {                                         \
      int off = rr * 8192 + tid * 16;                                        \
      int rh = off >> 7;                                                     \
      int r = ((rh >> 6) << 7) + (h) * 64 + (rh & 63);                       \
      int cb = (off & 127) ^ ((r & 7) << 4);                                 \
      g2l16((const char*)Ag + (long)r * 2048 + (t) * 128 + cb,               \
            (sl) + (h) * 16384 + off);                                       \
    } } while (0)

#define STGB(sl, t, h) do {                                                  \
    _Pragma("unroll")                                                        \
    for (int rr = 0; rr < 2; ++rr) {                                         \
      int off = rr * 8192 + tid * 16;                                        \
      int rh = off >> 7;                                                     \
      int r = ((rh >> 5) << 6) + (h) * 32 + (rh & 31);                       \
      int cb = (off & 127) ^ ((r & 7) << 4);                                 \
      g2l16((const char*)Bg + (long)r * 2048 + (t) * 128 + cb,               \
            (sl) + (h) * 16384 + off);                                       \
    } } while (0)

#define RDA(sl, mh) do {                                                     \
    _Pragma("unroll")                                                        \
    for (int m = 0; m < 4; ++m) {                                            \
      int ro = (wm * 64 + m * 16 + l15) * 128 + (mh) * 16384;                \
      a[m][0] = *(const bf16x8*)((sl) + ro + cb0);                           \
      a[m][1] = *(const bf16x8*)((sl) + ro + cb1);                           \
    } } while (0)

#define RDB(sl, nh) do {                                                     \
    _Pragma("unroll")                                                        \
    for (int n = 0; n < 2; ++n) {                                            \
      int ro = (wn * 32 + n * 16 + l15) * 128 + (nh) * 16384;                \
      b[nh][n][0] = *(const bf16x8*)((sl) + ro + cb0);                       \
      b[nh][n][1] = *(const bf16x8*)((sl) + ro + cb1);                       \
    } } while (0)

// 32-MFMA cluster: one A-half (mh) x full B (both nh quadrants)
#define MM2(mh) do {                                                         \
    __builtin_amdgcn_s_setprio(1);                                           \
    _Pragma("unroll")                                                        \
    for (int m = 0; m < 4; ++m)                                              \
      _Pragma("unroll")                                                      \
      for (int nh = 0; nh < 2; ++nh)                                         \
        _Pragma("unroll")                                                    \
        for (int n = 0; n < 2; ++n) {                                        \
          acc[(mh)*4+m][nh*2+n] = __builtin_amdgcn_mfma_f32_16x16x32_bf16(   \
              a[m][0], b[nh][n][0], acc[(mh)*4+m][nh*2+n], 0, 0, 0);         \
          acc[(mh)*4+m][nh*2+n] = __builtin_amdgcn_mfma_f32_16x16x32_bf16(   \
              a[m][1], b[nh][n][1], acc[(mh)*4+m][nh*2+n], 0, 0, 0);         \
        }                                                                    \
    __builtin_amdgcn_s_setprio(0);                                           \
  } while (0)

#define SB  __builtin_amdgcn_sched_barrier(0)
#define BAR __builtin_amdgcn_s_barrier()
// one gate per phase: no ds_read may cross in either direction
#define GATE(n) do { SB;                                                     \
    asm volatile("s_waitcnt vmcnt(" #n ")" ::: "memory");                    \
    BAR; SB; } while (0)

  // prologue: 14 loads, FIFO-ordered 6/2/6 so steady-state vmcnt(8) holds.
  STGA(lA0, 0, 0); STGB(lB0, 0, 0); STGB(lB0, 0, 1);   // ph1(j0) reads
  STGA(lA0, 0, 1);                                     // ph2(j0) reads
  STGA(lA1, 1, 0); STGB(lB1, 1, 0); STGB(lB1, 1, 1);   // ph3(j0) reads
  GATE(8);                                             // first 6 landed

  #pragma unroll 1
  for (int j = 0; j < 8; ++j) {
    const int ta2 = 2 * j + 2, tb2 = 2 * j + 3;
    const bool pf = (j < 7);
    // ---- ph1: stage A1.h1(2j+1); read slot0 A.h0 + B(all); MM(0,*)
    STGA(lA1, 2 * j + 1, 1);
    RDA(lA0, 0); RDB(lB0, 0); RDB(lB0, 1);
    MM2(0);
    GATE(8);
    // ---- ph2: stage A0.h0 + B0(both) of ta2; read slot0 A.h1; MM(1,*)
    if (pf) { STGA(lA0, ta2, 0); STGB(lB0, ta2, 0); STGB(lB0, ta2, 1); }
    RDA(lA0, 1);
    MM2(1);
    if (pf) GATE(8); else GATE(2);
    // ---- ph3: stage A0.h1(ta2); read slot1 A.h0 + B(all); MM(0,*)
    if (pf) STGA(lA0, ta2, 1);
    RDA(lA1, 0); RDB(lB1, 0); RDB(lB1, 1);
    MM2(0);
    if (pf) GATE(8); else GATE(0);
    // ---- ph4: stage A1.h0 + B1(both) of tb2; read slot1 A.h1; MM(1,*)
    if (pf) { STGA(lA1, tb2, 0); STGB(lB1, tb2, 0); STGB(lB1, tb2, 1); }
    RDA(lA1, 1);
    MM2(1);
    if (pf) GATE(8); else GATE(0);
  }

  // ============== epilogue: E-partial = relu(acc+b1) @ W2slice ===========
  // P per-wave region (16 KB), swizzled like main loop.
  char* Pw = LDS + wid * 16384;
  #pragma unroll
  for (int n = 0; n < 4; ++n) {
    const float bias = b1[tn * 256 + wn * 64 + n * 16 + l15];
    #pragma unroll
    for (int mr = 0; mr < 8; ++mr) {
      #pragma unroll
      for (int jj = 0; jj < 4; ++jj) {
        int row = mr * 16 + cg * 4 + jj;   // 0..127 within wave
        float v = acc[mr][n][jj] + bias;
        v = v > 0.f ? v : 0.f;
        int cbyte = ((n * 16 + l15) * 2) ^ ((row & 7) << 4);
        *(u16*)(Pw + row * 128 + cbyte) = (u16)bfr(v);
      }
    }
  }
  // B-frags: W2^T[q = l15][k within this wave's 64-col slice]
  const u16* w2p = w2t + l15 * 2048 + tn * 256 + wn * 64;
  bf16x8 bw0 = *(const bf16x8*)(w2p + cg * 8);
  bf16x8 bw1 = *(const bf16x8*)(w2p + 32 + cg * 8);
  f32x4 acc2[8];
  #pragma unroll
  for (int mf = 0; mf < 8; ++mf) {
    bf16x8 a0 = *(const bf16x8*)(Pw + (mf * 16 + l15) * 128 + ((cg * 16) ^ key));
    bf16x8 a1 = *(const bf16x8*)(Pw + (mf * 16 + l15) * 128 + ((64 + cg * 16) ^ key));
    f32x4 z = {0.f, 0.f, 0.f, 0.f};
    z = __builtin_amdgcn_mfma_f32_16x16x32_bf16(a0, bw0, z, 0, 0, 0);
    z = __builtin_amdgcn_mfma_f32_16x16x32_bf16(a1, bw1, z, 0, 0, 0);
    acc2[mf] = z;
  }
  __syncthreads();   // all P reads done before Ew overwrites LDS
  // Ew[wm][128 rows][16 q x 4 wn (+4 pad)] f32, stride 68
  float* Ew = (float*)LDS;
  #pragma unroll
  for (int mf = 0; mf < 8; ++mf)
    #pragma unroll
    for (int rg = 0; rg < 4; ++rg)
      Ew[(wm * 128 + mf * 16 + cg * 4 + rg) * 68 + l15 * 4 + wn] = acc2[mf][rg];
  __syncthreads();
  // reduce over wn, store Ep[tn][tm*256 + wmh*128 + row][q]
  #pragma unroll
  for (int c = tid; c < 4096; c += 512) {
    int wmh = c >> 11, row = (c >> 4) & 127, q = c & 15;
    const float* e4 = &Ew[(wmh * 128 + row) * 68 + q * 4];
    float s = e4[0] + e4[1] + e4[2] + e4[3];
    Ep[(long)tn * (16384 * 16) + (long)(tm * 256 + wmh * 128 + row) * 16 + q] = s;
  }
#undef STGA
#undef STGB
#undef RDA
#undef RDB
#undef MM2
#undef SB
#undef BAR
#undef GATE
}

// ---------------- final: sum Ep, +b2, tanh, sin, VQC, sigmoid -------------
__global__ __launch_bounds__(256) void vqc_final(
    const float* __restrict__ Ep, const float* __restrict__ b2,
    const float* __restrict__ vqc, const float* __restrict__ Wd,
    const float* __restrict__ bd, float* __restrict__ out) {
  const int tid = threadIdx.x;
  const int lane = tid & 63;
  const int wave = tid >> 6;
  const int q = lane & 15;
  const int g = lane >> 4;
  const int row = blockIdx.x * 16 + wave * 4 + g;

  float e = 0.f;
  #pragma unroll
  for (int p = 0; p < 8; ++p)
    e += Ep[(long)p * (16384 * 16) + (long)row * 16 + q];

  float ct[6], sp[6];
  #pragma unroll
  for (int L = 0; L < 6; ++L) {
    float th = vqc[(L * 16 + q) * 2 + 0];
    float ph = vqc[(L * 16 + q) * 2 + 1];
    ct[L] = __cosf(th);
    sp[L] = __sinf(th) * __cosf(ph);
  }
  float s = __sinf(tanhf(e + b2[q]) * PI_F);
  #pragma unroll
  for (int L = 0; L < 6; ++L) {
    s = ct[L] * s + sp[L];
    if (L < 5) {
      float ps = __shfl_xor(s, 1, 64);
      s = (q & 1) ? (0.1f * ps + 0.9f * s) : s;
    }
  }
  float p = s * Wd[q];
  p += __shfl_xor(p, 1, 64);
  p += __shfl_xor(p, 2, 64);
  p += __shfl_xor(p, 4, 64);
  p += __shfl_xor(p, 8, 64);
  if (q == 0) out[row] = 1.f / (1.f + __expf(-(p + bd[0])));
}

// ---------------- fp32 fallback (ws too small): slow but correct ---------
__global__ __launch_bounds__(256) void fallback(
    const float* __restrict__ x, const float* __restrict__ W1,
    const float* __restrict__ b1, const float* __restrict__ W2,
    const float* __restrict__ b2, const float* __restrict__ vqc,
    const float* __restrict__ Wd, const float* __restrict__ bd,
    float* __restrict__ out) {
  __shared__ float xs[4][1024];
  __shared__ float E[4][16];
  const int bid = blockIdx.x;
  const int tid = threadIdx.x;
  const int r0 = bid * 4;
  for (int i = tid; i < 4 * 1024; i += 256)
    xs[i >> 10][i & 1023] = x[(long)(r0 + (i >> 10)) * 1024 + (i & 1023)];
  if (tid < 64) ((float*)E)[tid] = 0.f;
  __syncthreads();
  float pE[4][16];
  #pragma unroll
  for (int r = 0; r < 4; ++r)
    #pragma unroll
    for (int qq = 0; qq < 16; ++qq) pE[r][qq] = 0.f;
  for (int jj = 0; jj < 8; ++jj) {
    int j = jj * 256 + tid;
    float h0 = 0, h1 = 0, h2 = 0, h3 = 0;
    for (int k = 0; k < 1024; ++k) {
      float w = W1[(long)k * 2048 + j];
      h0 += xs[0][k] * w; h1 += xs[1][k] * w; h2 += xs[2][k] * w; h3 += xs[3][k] * w;
    }
    float hh[4] = {h0, h1, h2, h3};
    #pragma unroll
    for (int r = 0; r < 4; ++r) {
      float hr = hh[r] + b1[j];
      hr = hr > 0.f ? hr : 0.f;
      #pragma unroll
      for (int qq = 0; qq < 16; ++qq) pE[r][qq] += hr * W2[j * 16 + qq];
    }
  }
  #pragma unroll
  for (int r = 0; r < 4; ++r)
    #pragma unroll
    for (int qq = 0; qq < 16; ++qq) atomicAdd(&E[r][qq], pE[r][qq]);
  __syncthreads();
  if (tid < 4) {
    int r = tid;
    float s[16];
    #pragma unroll
    for (int qq = 0; qq < 16; ++qq)
      s[qq] = __sinf(tanhf(E[r][qq] + b2[qq]) * PI_F);
    #pragma unroll
    for (int L = 0; L < 6; ++L) {
      #pragma unroll
      for (int qq = 0; qq < 16; ++qq)
        s[qq] = __cosf(vqc[(L * 16 + qq) * 2]) * s[qq] +
                __sinf(vqc[(L * 16 + qq) * 2]) * __cosf(vqc[(L * 16 + qq) * 2 + 1]);
      if (L < 5)
        #pragma unroll
        for (int qq = 1; qq < 16; qq += 2) s[qq] = 0.1f * s[qq - 1] + 0.9f * s[qq];
    }
    float z = bd[0];
    #pragma unroll
    for (int qq = 0; qq < 16; ++qq) z += s[qq] * Wd[qq];
    out[r0 + r] = 1.f / (1.f + __expf(-z));
  }
}

extern "C" void kernel_launch(void* const* d_in, const int* in_sizes, int n_in,
                              void* d_out, int out_size, void* d_ws, size_t ws_size,
                              hipStream_t stream) {
  const float* x   = (const float*)d_in[0];
  const float* W1  = (const float*)d_in[1];
  const float* b1  = (const float*)d_in[2];
  const float* W2  = (const float*)d_in[3];
  const float* b2  = (const float*)d_in[4];
  const float* vqc = (const float*)d_in[5];
  const float* Wd  = (const float*)d_in[6];
  const float* bd  = (const float*)d_in[7];
  float* out = (float*)d_out;

  const size_t OFF_XB  = 0;                         // 33554432
  const size_t OFF_W1T = 33554432;                  // +4194304
  const size_t OFF_W2T = 37748736;                  // +65536
  const size_t OFF_EP  = 37814272;                  // +8388608
  const size_t NEED    = 46202880;

  if (ws_size < NEED) {
    fallback<<<4096, 256, 0, stream>>>(x, W1, b1, W2, b2, vqc, Wd, bd, out);
    return;
  }
  u16*   xb  = (u16*)((char*)d_ws + OFF_XB);
  u16*   w1t = (u16*)((char*)d_ws + OFF_W1T);
  u16*   w2t = (u16*)((char*)d_ws + OFF_W2T);
  float* Ep  = (float*)((char*)d_ws + OFF_EP);

  cvt_all<<<8704, 256, 0, stream>>>(x, W1, W2, xb, w1t, w2t);
  gemm1_fused<<<512, 512, 0, stream>>>(xb, w1t, b1, w2t, Ep);
  vqc_final<<<1024, 256, 0, stream>>>(Ep, b2, vqc, Wd, bd, out);
}